// Round 13
// baseline (107.672 us; speedup 1.0000x reference)
//
#include <hip/hip_runtime.h>

// AdaptiveAngleConv round 13: single main kernel (no xt pass), 16 waves/CU,
// reg-staged bf16 conversion under a drain-free R11-style schedule.
//   - full-width 2-row tiles, ring of 4 full-width rows, acc 64/wave
//   - natural x-tap order (dh ascending): old slots done at t=5 -> mid-K
//     barrier at t=6, pack+ds_write overlaps K tail, publish at tile-end
//   - restage loads issued BEFORE NT stores -> counted vmcnt, no store drain
//   - bias as 37th K-step; readfirstlane'd wave coords -> tables in SGPRs
// LDS: A 75,776 + ring 4*16,640 = 142,336 B. 256 blocks x 1024 thr.

#define CIN 64
#define COUT 64
#define HH 128
#define WW 128
#define NB 16
#define HW (HH*WW)

typedef short bf16x8 __attribute__((ext_vector_type(8)));
typedef float f32x16 __attribute__((ext_vector_type(16)));
#define AS1 __attribute__((address_space(1)))
#define AS3 __attribute__((address_space(3)))

// APERM_d[a][t] = PERMS[a][t] * 8192 : A slab byte offset paired with x-tap t
// (equivalent to the R4..R12-validated BOFF pairing, re-indexed by x-tap).
__device__ __constant__ unsigned APERM_d[4][9] = {
  {0,8192,16384,24576,32768,40960,49152,57344,65536},
  {24576,0,8192,49152,32768,16384,57344,65536,40960},
  {49152,24576,0,57344,32768,8192,65536,40960,16384},
  {57344,49152,24576,65536,32768,0,40960,16384,8192},
};

static __device__ __forceinline__ unsigned short f2bf(float f) {
  unsigned u = __builtin_bit_cast(unsigned, f);
  return (unsigned short)((u + 0x7FFFu + ((u >> 16) & 1u)) >> 16);
}
static __device__ __forceinline__ unsigned pk2(float lo, float hi) {
  return (unsigned)f2bf(lo) | ((unsigned)f2bf(hi) << 16);
}

// Canonical A + bias kstep (v9-validated): e = ((kc*2 + half)*64 + cm)*8 + j.
// kc<36: ci = (kc&3)*16 + half*8 + j, value W[cm][ci][kc>>2].
// kc==36: bias[cm] one-hot at (half==0, j==0). 37,888 bf16 = 75,776 B.
__global__ void build_A_kernel(const float* __restrict__ wgt,
                               const float* __restrict__ bias,
                               unsigned short* __restrict__ A) {
  const int e = blockIdx.x * 256 + threadIdx.x;
  const int j = e & 7;
  const int cm = (e >> 3) & 63;
  const int half = (e >> 9) & 1;
  const int kc = e >> 10;
  if (kc < 36) {
    const int s = kc >> 2, q = kc & 3;
    const int ci = q * 16 + half * 8 + j;
    A[e] = f2bf(wgt[(cm * CIN + ci) * 9 + s]);
  } else if (kc == 36) {
    A[e] = (half == 0 && j == 0) ? f2bf(bias[cm]) : (unsigned short)0;
  }
}

// ring: slot(x_row r) = (r+1)&3 ; byte(rs, ci, wI) = XS_OFF + rs*XS_ROW +
//   (ci>>3)*XS_SLOT + wI*16 + (ci&7)*2 ; wI = 0..129 = x col -1..128.
#define XS_SLOT 2080
#define XS_ROW  16640
#define XS_OFF  75776
#define LDS_BYTES (XS_OFF + 4 * XS_ROW)   // 142,336 B

__global__ __launch_bounds__(1024, 4) void aconv_v13_kernel(
    const float* __restrict__ x,              // [B][CIN][H][W] fp32
    const unsigned short* __restrict__ Ag,    // 37 kc canonical + bias
    float* __restrict__ out)                  // [4][B][COUT][H][W] fp32
{
  __shared__ __align__(16) unsigned char lds[LDS_BYTES];

  const int tid = threadIdx.x;
  const int lane = tid & 63;
  const int wid = tid >> 6;          // 16 waves
  const int a   = __builtin_amdgcn_readfirstlane(wid >> 2);        // angle (SGPR)
  const int row = __builtin_amdgcn_readfirstlane((wid >> 1) & 1);  // tile row (SGPR)
  const int wh  = __builtin_amdgcn_readfirstlane(wid & 1);         // w half (SGPR)
  const int half = lane >> 5;
  const int ln = lane & 31;

  const int b   = blockIdx.x >> 4;
  const int rem = blockIdx.x & 15;
  const int hbase = rem * 8;

  const unsigned char* Agb = (const unsigned char*)Ag;
  AS3 unsigned char* ldsa = (AS3 unsigned char*)lds;
  const uint4 z4 = {0u, 0u, 0u, 0u};

  // ---- stage A via global_load_lds (zero staging VGPRs) ----
  #pragma unroll
  for (int j = 0; j < 5; ++j) {
    const int i = wid + j * 16;
    if (i < 74)
      __builtin_amdgcn_global_load_lds(
          (const AS1 unsigned*)(Agb + i * 1024 + lane * 16),
          (AS3 unsigned*)(ldsa + i * 1024), 16, 0, 0);
  }
  // ---- permanent-zero w borders (wI = 0, 129), all 4 ring slots ----
  if (tid < 64) {
    const int rs = tid >> 4, cs = (tid >> 1) & 7, side = tid & 1;
    *(uint4*)(lds + XS_OFF + rs * XS_ROW + cs * XS_SLOT + side * 129 * 16) = z4;
  }

  // ---- per-thread staging geometry (1 granule per row): (slot, col) ----
  const int sslot = (tid >> 7) & 7;
  const int swc   = tid & 127;
  const float* sxb = x + (size_t)(b * CIN + sslot * 8) * HW + swc;
  const unsigned sdstb = (unsigned)(XS_OFF + sslot * XS_SLOT + (1 + swc) * 16);

  // ---- prologue: stage rows hbase-1 .. hbase+2 into slots 0..3 ----
  #pragma unroll
  for (int i = 0; i < 4; ++i) {
    const int gh = hbase - 1 + i;
    const bool inb = (unsigned)gh < HH;
    const float* xp = sxb + (size_t)gh * WW;
    float v[8];
    #pragma unroll
    for (int q = 0; q < 8; ++q) v[q] = inb ? xp[(size_t)q * HW] : 0.f;
    uint4 u;
    u.x = pk2(v[0], v[1]); u.y = pk2(v[2], v[3]);
    u.z = pk2(v[4], v[5]); u.w = pk2(v[6], v[7]);
    *(uint4*)(lds + sdstb + i * XS_ROW) = u;
  }
  __syncthreads();   // A glls + prologue ds_writes visible

  // issue restage loads for rows hbase+3, hbase+4 (packed at tile0 t==6)
  float gv[2][8];
  #pragma unroll
  for (int i = 0; i < 2; ++i) {
    const int gh = hbase + 3 + i;
    const bool inb = (unsigned)gh < HH;
    const float* xp = sxb + (size_t)gh * WW;
    #pragma unroll
    for (int q = 0; q < 8; ++q) gv[i][q] = inb ? xp[(size_t)q * HW] : 0.f;
  }

  const unsigned char* Asb = lds + (unsigned)(half * 1024 + ln * 16);
  const unsigned char* Bsb = lds + XS_OFF + (unsigned)(half * XS_SLOT + (wh * 64 + ln) * 16);

  bf16x8 ob = (bf16x8)(short)0;      // one-hot B frag for bias kstep
  if (half == 0) ob[0] = (short)0x3F80;

  #pragma unroll 1
  for (int it = 0; it < 4; ++it) {
    // ring byte offsets per dh (SGPR arithmetic: it, row wave-uniform)
    const int rowbase = it * 2 + row;
    unsigned ro[3];
    #pragma unroll
    for (int dh = 0; dh < 3; ++dh)
      ro[dh] = (unsigned)(((rowbase + dh) & 3) * XS_ROW);

    f32x16 acc[2][2];
    #pragma unroll
    for (int mf = 0; mf < 2; ++mf)
      #pragma unroll
      for (int nf = 0; nf < 2; ++nf) acc[mf][nf] = (f32x16)(0.f);

    #pragma unroll
    for (int t = 0; t < 9; ++t) {
      if (t == 6) {
        // old slots (rows it*2-1, it*2) fully read by all waves after t=5
        asm volatile("s_waitcnt lgkmcnt(0)" ::: "memory");
        __builtin_amdgcn_s_barrier();
        if (it < 3) {
          // pack + write rows it*2+3, it*2+4 into the just-freed slots;
          // vmcnt wait here is counted (stores were issued BEFORE these
          // loads only in earlier tiles -> loads are oldest, stores newer)
          #pragma unroll
          for (int i = 0; i < 2; ++i) {
            const int gh = hbase + it * 2 + 3 + i;
            uint4 u = z4;
            if (gh < HH) {
              u.x = pk2(gv[i][0], gv[i][1]); u.y = pk2(gv[i][2], gv[i][3]);
              u.z = pk2(gv[i][4], gv[i][5]); u.w = pk2(gv[i][6], gv[i][7]);
            }
            *(uint4*)(lds + sdstb + (unsigned)(((it * 2 + i) & 3) * XS_ROW)) = u;
          }
        }
      }
      const unsigned aoff = APERM_d[a][t];           // SGPR (a uniform)
      const unsigned bbt = ro[t / 3] + (unsigned)((t % 3) * 16);
      #pragma unroll
      for (int q = 0; q < 4; ++q) {
        const bf16x8 af0 = *(const bf16x8*)(Asb + aoff + q * 2048);
        const bf16x8 af1 = *(const bf16x8*)(Asb + aoff + q * 2048 + 512);
        const unsigned bb = bbt + (unsigned)(q * 2 * XS_SLOT);
        const bf16x8 bf0 = *(const bf16x8*)(Bsb + bb);
        const bf16x8 bf1 = *(const bf16x8*)(Bsb + bb + 512);
        acc[0][0] = __builtin_amdgcn_mfma_f32_32x32x16_bf16(af0, bf0, acc[0][0], 0, 0, 0);
        acc[0][1] = __builtin_amdgcn_mfma_f32_32x32x16_bf16(af0, bf1, acc[0][1], 0, 0, 0);
        acc[1][0] = __builtin_amdgcn_mfma_f32_32x32x16_bf16(af1, bf0, acc[1][0], 0, 0, 0);
        acc[1][1] = __builtin_amdgcn_mfma_f32_32x32x16_bf16(af1, bf1, acc[1][1], 0, 0, 0);
      }
    }
    {  // bias kstep: one-hot B adds bias[cm] to every column
      const bf16x8 af0 = *(const bf16x8*)(Asb + 36 * 2048);
      const bf16x8 af1 = *(const bf16x8*)(Asb + 36 * 2048 + 512);
      acc[0][0] = __builtin_amdgcn_mfma_f32_32x32x16_bf16(af0, ob, acc[0][0], 0, 0, 0);
      acc[0][1] = __builtin_amdgcn_mfma_f32_32x32x16_bf16(af0, ob, acc[0][1], 0, 0, 0);
      acc[1][0] = __builtin_amdgcn_mfma_f32_32x32x16_bf16(af1, ob, acc[1][0], 0, 0, 0);
      acc[1][1] = __builtin_amdgcn_mfma_f32_32x32x16_bf16(af1, ob, acc[1][1], 0, 0, 0);
    }

    // issue next restage loads BEFORE the stores (counted-vmcnt pack later)
    if (it < 2) {
      #pragma unroll
      for (int i = 0; i < 2; ++i) {
        const int gh = hbase + it * 2 + 5 + i;
        const bool inb = (unsigned)gh < HH;
        const float* xp = sxb + (size_t)gh * WW;
        #pragma unroll
        for (int q = 0; q < 8; ++q) gv[i][q] = inb ? xp[(size_t)q * HW] : 0.f;
      }
    }

    // NT stores (fire-and-forget; never gate a barrier)
    const int hout = hbase + it * 2 + row;
    #pragma unroll
    for (int mf = 0; mf < 2; ++mf)
      #pragma unroll
      for (int nf = 0; nf < 2; ++nf) {
        const f32x16 v = acc[mf][nf];
        float* op = out + (((size_t)(a * NB + b) * COUT + mf * 32 + 4 * half) * HH
                           + hout) * WW + wh * 64 + nf * 32 + ln;
        #pragma unroll
        for (int g = 0; g < 16; ++g)
          __builtin_nontemporal_store(v[g], op + (size_t)((g & 3) + 8 * (g >> 2)) * HW);
      }

    // tile-end publish barrier (lgkm only)
    asm volatile("s_waitcnt lgkmcnt(0)" ::: "memory");
    __builtin_amdgcn_s_barrier();
  }
}

extern "C" void kernel_launch(void* const* d_in, const int* in_sizes, int n_in,
                              void* d_out, int out_size, void* d_ws, size_t ws_size,
                              hipStream_t stream) {
  const float* x    = (const float*)d_in[0];
  const float* wgt  = (const float*)d_in[1];
  const float* bias = (const float*)d_in[2];
  float* out = (float*)d_out;
  unsigned short* A = (unsigned short*)d_ws;   // 75,776 B

  build_A_kernel<<<148, 256, 0, stream>>>(wgt, bias, A);
  aconv_v13_kernel<<<256, 1024, 0, stream>>>(x, A, out);
}

// Round 14
// 98.401 us; speedup vs baseline: 1.0942x; 1.0942x over previous
//
#include <hip/hip_runtime.h>

// AdaptiveAngleConv round 14: R7 with w-half interleaving.
//   - ring of 4 FULL-WIDTH x rows (130 granules/slot-row, stride 2080 - v13 layout)
//   - tile order (it, wh) wh-inner: x fetched ONCE, restage = 2 full rows every
//     other tile, NO barrier between the two w-halves of one it -> 6 barriers/block
//   - loads at odd-tile K-start, pack after that tile's lgkm barrier (counted vmcnt)
//   - gll A-staging, bv bias init, NT stores, acc 64 AGPR, 512 thr / 8 waves.
// LDS: A 73,728 + ring 4*16,640 = 140,288 B.

#define CIN 64
#define COUT 64
#define HH 128
#define WW 128
#define NB 16
#define HW (HH*WW)

typedef short bf16x8 __attribute__((ext_vector_type(8)));
typedef float f32x16 __attribute__((ext_vector_type(16)));
#define AS1 __attribute__((address_space(1)))
#define AS3 __attribute__((address_space(3)))

// APERM_d[a][t] = PERMS[a][t] * 8192 : A slab byte offset paired with x-tap t
// (v13-validated, absmax 0.5).
__device__ __constant__ unsigned APERM_d[4][9] = {
  {0,8192,16384,24576,32768,40960,49152,57344,65536},
  {24576,0,8192,49152,32768,16384,57344,65536,40960},
  {49152,24576,0,57344,32768,8192,65536,40960,16384},
  {57344,49152,24576,65536,32768,0,40960,16384,8192},
};

static __device__ __forceinline__ unsigned short f2bf(float f) {
  unsigned u = __builtin_bit_cast(unsigned, f);
  return (unsigned short)((u + 0x7FFFu + ((u >> 16) & 1u)) >> 16);
}
static __device__ __forceinline__ unsigned pk2(float lo, float hi) {
  return (unsigned)f2bf(lo) | ((unsigned)f2bf(hi) << 16);
}

// Canonical A (R4..R13-validated): e = ((kc*2 + half)*64 + cm)*8 + j ; kc = s*4+q ;
// ci = q*16 + half*8 + j ; value = W[cm][ci][s]. 36,864 bf16 = 73,728 B.
__global__ void build_A_kernel(const float* __restrict__ wgt,
                               unsigned short* __restrict__ A) {
  const int e = blockIdx.x * 256 + threadIdx.x;
  const int j = e & 7;
  const int cm = (e >> 3) & 63;
  const int half = (e >> 9) & 1;
  const int kc = e >> 10;
  const int s = kc >> 2, q = kc & 3;
  const int ci = q * 16 + half * 8 + j;
  A[e] = f2bf(wgt[(cm * CIN + ci) * 9 + s]);
}

static __device__ __forceinline__ void lgkm_barrier() {
  asm volatile("s_waitcnt lgkmcnt(0)" ::: "memory");
  __builtin_amdgcn_s_barrier();
}

// ring: byte(rs, ci, wI) = XS_OFF + rs*XS_ROW + (ci>>3)*XS_SLOT + wI*16 + (ci&7)*2
//   rs = ring slot; x row hx -> slot (hx - hbase + 1) & 3 ; wI = 0..129 = x col -1..128
#define XS_SLOT 2080
#define XS_ROW  16640
#define XS_OFF  73728
#define LDS_BYTES (XS_OFF + 4 * XS_ROW)   // 140,288 B

__global__ __launch_bounds__(512) void aconv_v14_kernel(
    const float* __restrict__ x,              // [B][CIN][H][W] fp32
    const unsigned short* __restrict__ Ag,    // canonical W, 36,864 bf16
    const float* __restrict__ bias,           // [COUT]
    float* __restrict__ out)                  // [4][B][COUT][H][W] fp32
{
  __shared__ __align__(16) unsigned char lds[LDS_BYTES];

  const int tid = threadIdx.x;
  const int lane = tid & 63;
  const int wid = tid >> 6;          // 8 waves
  const int a   = wid >> 1;          // angle
  const int row = wid & 1;           // output row within 2-row tile
  const int half = lane >> 5;
  const int ln = lane & 31;

  const int b   = blockIdx.x >> 4;
  const int rem = blockIdx.x & 15;
  const int hbase = rem * 8;

  const unsigned char* Agb = (const unsigned char*)Ag;
  AS3 unsigned char* ldsa = (AS3 unsigned char*)lds;
  const uint4 z4 = {0u, 0u, 0u, 0u};

  // ---- stage A via global_load_lds: 72 granules of 1024 B (zero staging VGPRs) ----
  #pragma unroll
  for (int j = 0; j < 9; ++j) {
    const int i = wid + j * 8;       // 0..71
    __builtin_amdgcn_global_load_lds(
        (const AS1 unsigned*)(Agb + i * 1024 + lane * 16),
        (AS3 unsigned*)(ldsa + i * 1024), 16, 0, 0);
  }

  // ---- bias fragments ----
  float bv[2][16];
  #pragma unroll
  for (int mf = 0; mf < 2; ++mf)
    #pragma unroll
    for (int g = 0; g < 16; ++g)
      bv[mf][g] = bias[mf * 32 + (g & 3) + 8 * (g >> 2) + 4 * half];

  // ---- prologue: stage x rows hbase-1..hbase+2 (full width) into slots 0..3 ----
  // 4 rows x 8 slots x 130 cols = 4160 granules (16 B each)
  #pragma unroll
  for (int i = 0; i < 9; ++i) {
    const int g = tid + i * 512;
    if (g < 4160) {
      const int r    = g / 1040;
      const int rest = g - r * 1040;
      const int slot = rest / 130;
      const int wI   = rest - slot * 130;
      const int gh = hbase - 1 + r;
      const int gw = wI - 1;
      const bool inb = ((unsigned)gh < HH) && ((unsigned)gw < WW);
      const float* xp = x + (size_t)(b * CIN + slot * 8) * HW + (size_t)gh * WW + gw;
      float v[8];
      #pragma unroll
      for (int q = 0; q < 8; ++q) v[q] = inb ? xp[(size_t)q * HW] : 0.f;
      uint4 u;
      u.x = pk2(v[0], v[1]); u.y = pk2(v[2], v[3]);
      u.z = pk2(v[4], v[5]); u.w = pk2(v[6], v[7]);
      *(uint4*)(lds + XS_OFF + r * XS_ROW + slot * XS_SLOT + wI * 16) = u;
    }
  }
  __syncthreads();   // A glls (vmcnt) + prologue ds_writes (lgkm) all visible

  const unsigned char* Asb = lds + (unsigned)(half * 1024 + ln * 16);
  const unsigned char* Bsb = lds + XS_OFF + (unsigned)(half * XS_SLOT + ln * 16);

  float gv[5][8];    // restage registers (live only across odd tiles)

  #pragma unroll 1
  for (int ti = 0; ti < 8; ++ti) {
    const int it = ti >> 1;          // h pair 0..3
    const int wh = ti & 1;           // w half (inner)
    const bool odd = (wh == 1);
    const bool rst = odd && (it < 3);

    // ring byte offsets per dh: x row hbase+it*2+row-1+dh -> slot (it*2+row+dh)&3
    unsigned ro[3];
    #pragma unroll
    for (int dh = 0; dh < 3; ++dh)
      ro[dh] = (unsigned)(((it * 2 + row + dh) & 3) * XS_ROW);

    // issue restage loads at odd-tile start: rows hbase+it*2+3, +4 (full width)
    // 2 rows x 8 slots x 130 cols = 2080 granules
    if (rst) {
      #pragma unroll
      for (int i = 0; i < 5; ++i) {
        const int g = tid + i * 512;
        if (g < 2080) {
          const int rr   = g / 1040;
          const int rest = g - rr * 1040;
          const int slot = rest / 130;
          const int wI   = rest - slot * 130;
          const int gh = hbase + it * 2 + 3 + rr;
          const int gw = wI - 1;
          const bool inb = ((unsigned)gh < HH) && ((unsigned)gw < WW);
          const float* xp = x + (size_t)(b * CIN + slot * 8) * HW + (size_t)gh * WW + gw;
          #pragma unroll
          for (int q = 0; q < 8; ++q) gv[i][q] = inb ? xp[(size_t)q * HW] : 0.f;
        }
      }
    }

    // ---- acc init with bias; K-loop: 9 taps x 4 q-steps ----
    f32x16 acc[2][2];
    #pragma unroll
    for (int mf = 0; mf < 2; ++mf)
      #pragma unroll
      for (int nf = 0; nf < 2; ++nf)
        #pragma unroll
        for (int g = 0; g < 16; ++g)
          acc[mf][nf][g] = bv[mf][g];

    const unsigned whb = (unsigned)(wh * 64 * 16);
    #pragma unroll
    for (int t = 0; t < 9; ++t) {
      const unsigned aoff = APERM_d[a][t];
      const unsigned bbt = ro[t / 3] + (unsigned)((t % 3) * 16) + whb;
      #pragma unroll
      for (int q = 0; q < 4; ++q) {
        const bf16x8 af0 = *(const bf16x8*)(Asb + aoff + q * 2048);
        const bf16x8 af1 = *(const bf16x8*)(Asb + aoff + q * 2048 + 512);
        const unsigned bb = bbt + (unsigned)(q * 2 * XS_SLOT);
        const bf16x8 bf0 = *(const bf16x8*)(Bsb + bb);
        const bf16x8 bf1 = *(const bf16x8*)(Bsb + bb + 512);
        acc[0][0] = __builtin_amdgcn_mfma_f32_32x32x16_bf16(af0, bf0, acc[0][0], 0, 0, 0);
        acc[0][1] = __builtin_amdgcn_mfma_f32_32x32x16_bf16(af0, bf1, acc[0][1], 0, 0, 0);
        acc[1][0] = __builtin_amdgcn_mfma_f32_32x32x16_bf16(af1, bf0, acc[1][0], 0, 0, 0);
        acc[1][1] = __builtin_amdgcn_mfma_f32_32x32x16_bf16(af1, bf1, acc[1][1], 0, 0, 0);
      }
    }

    // ---- NT stores (fire-and-forget; never gate a barrier) ----
    const int hout = hbase + it * 2 + row;
    #pragma unroll
    for (int mf = 0; mf < 2; ++mf)
      #pragma unroll
      for (int nf = 0; nf < 2; ++nf) {
        const f32x16 v = acc[mf][nf];
        float* op = out + (((size_t)(a * NB + b) * COUT + mf * 32 + 4 * half) * HH
                           + hout) * WW + wh * 64 + nf * 32 + ln;
        #pragma unroll
        for (int g = 0; g < 16; ++g)
          __builtin_nontemporal_store(v[g], op + (size_t)((g & 3) + 8 * (g >> 2)) * HW);
      }

    // ---- barrier pair + pack only after odd tiles (except the last) ----
    if (rst) {
      lgkm_barrier();                // all waves' ring reads complete (lgkm only)
      #pragma unroll
      for (int i = 0; i < 5; ++i) {
        const int g = tid + i * 512;
        if (g < 2080) {
          const int rr   = g / 1040;
          const int rest = g - rr * 1040;
          const int slot = rest / 130;
          const int wI   = rest - slot * 130;
          // x row hbase+it*2+3+rr -> ring slot (it*2+4+rr)&3
          uint4 u;
          u.x = pk2(gv[i][0], gv[i][1]); u.y = pk2(gv[i][2], gv[i][3]);
          u.z = pk2(gv[i][4], gv[i][5]); u.w = pk2(gv[i][6], gv[i][7]);
          *(uint4*)(lds + XS_OFF + (unsigned)(((it * 2 + 4 + rr) & 3) * XS_ROW)
                    + slot * XS_SLOT + wI * 16) = u;
        }
      }
      lgkm_barrier();                // new rows visible for it+1
    }
  }
}

extern "C" void kernel_launch(void* const* d_in, const int* in_sizes, int n_in,
                              void* d_out, int out_size, void* d_ws, size_t ws_size,
                              hipStream_t stream) {
  const float* x    = (const float*)d_in[0];
  const float* wgt  = (const float*)d_in[1];
  const float* bias = (const float*)d_in[2];
  float* out = (float*)d_out;
  unsigned short* A = (unsigned short*)d_ws;   // 73,728 B

  build_A_kernel<<<144, 256, 0, stream>>>(wgt, A);
  aconv_v14_kernel<<<256, 512, 0, stream>>>(x, A, bias, out);
}